// Round 3
// baseline (25358.545 us; speedup 1.0000x reference)
//
#include <hip/hip_runtime.h>
#include <hip/hip_bf16.h>

typedef float v4f __attribute__((ext_vector_type(4)));
typedef int   v4i __attribute__((ext_vector_type(4)));

#define T_LEN 8192
#define E_DIM 1024
#define HD    512
#define G4    2048
#define K_TAGS 34

// ---------------- ws layout (bytes) ----------------
#define XP_OFF      0ull                  // 2 * 8192 * 2048 f32 = 128MB
#define HS_OFF      134217728ull          // 2 * 8192 * 512 f32  = 32MB
#define FEATS_OFF   167772160ull          // 8192*34 f32
#define BP_OFF      168886272ull          // 8192*34 u8
#define BEST_OFF    169165824ull          // int

// =========================================================
// xp GEMM: xp[dir][t][r] = sentence[t] . w_ih[dir][r] + b_ih[r]+b_hh[r]
// =========================================================
#define BM 128
#define BN 128
#define BKK 16

__global__ __launch_bounds__(256) void xp_gemm(
    const float* __restrict__ A, const float* __restrict__ Wf, const float* __restrict__ Wb,
    const float* __restrict__ bihf, const float* __restrict__ bhhf,
    const float* __restrict__ bihb, const float* __restrict__ bhhb,
    float* __restrict__ xp)
{
  __shared__ __align__(16) float a_lds[BKK][BM + 4];
  __shared__ __align__(16) float b_lds[BKK][BN + 4];
  const int dir = blockIdx.z;
  const float* W   = dir ? Wb : Wf;
  const float* bih = dir ? bihb : bihf;
  const float* bhh = dir ? bhhb : bhhf;
  const int tid = threadIdx.x;
  const int srow = tid >> 1, sh = (tid & 1) * 8;
  const int tx = tid & 15, ty = tid >> 4;
  const size_t arow = (size_t)(blockIdx.x * BM + srow) * E_DIM;
  const size_t brow = (size_t)(blockIdx.y * BN + srow) * E_DIM;
  float acc[8][8];
  #pragma unroll
  for (int i = 0; i < 8; ++i)
    #pragma unroll
    for (int j = 0; j < 8; ++j) acc[i][j] = 0.f;

  for (int k0 = 0; k0 < E_DIM; k0 += BKK) {
    v4f a0 = *(const v4f*)(A + arow + k0 + sh);
    v4f a1 = *(const v4f*)(A + arow + k0 + sh + 4);
    v4f b0 = *(const v4f*)(W + brow + k0 + sh);
    v4f b1 = *(const v4f*)(W + brow + k0 + sh + 4);
    __syncthreads();
    #pragma unroll
    for (int j = 0; j < 4; ++j) {
      a_lds[sh + j][srow]     = a0[j];
      a_lds[sh + 4 + j][srow] = a1[j];
      b_lds[sh + j][srow]     = b0[j];
      b_lds[sh + 4 + j][srow] = b1[j];
    }
    __syncthreads();
    #pragma unroll
    for (int kk = 0; kk < BKK; ++kk) {
      v4f av0 = *(const v4f*)&a_lds[kk][ty * 8];
      v4f av1 = *(const v4f*)&a_lds[kk][ty * 8 + 4];
      v4f bv0 = *(const v4f*)&b_lds[kk][tx * 4];
      v4f bv1 = *(const v4f*)&b_lds[kk][64 + tx * 4];
      float av[8] = {av0[0],av0[1],av0[2],av0[3],av1[0],av1[1],av1[2],av1[3]};
      float bv[8] = {bv0[0],bv0[1],bv0[2],bv0[3],bv1[0],bv1[1],bv1[2],bv1[3]};
      #pragma unroll
      for (int i = 0; i < 8; ++i)
        #pragma unroll
        for (int j = 0; j < 8; ++j) acc[i][j] = fmaf(av[i], bv[j], acc[i][j]);
    }
  }
  const int gm  = blockIdx.x * BM + ty * 8;
  const int gnl = blockIdx.y * BN + tx * 4;
  const int gnh = gnl + 64;
  float bias[8];
  #pragma unroll
  for (int j = 0; j < 4; ++j) bias[j]     = bih[gnl + j] + bhh[gnl + j];
  #pragma unroll
  for (int j = 0; j < 4; ++j) bias[4 + j] = bih[gnh + j] + bhh[gnh + j];
  float* outp = xp + ((size_t)dir * T_LEN) * G4;
  #pragma unroll
  for (int i = 0; i < 8; ++i) {
    v4f o0 = {acc[i][0]+bias[0], acc[i][1]+bias[1], acc[i][2]+bias[2], acc[i][3]+bias[3]};
    v4f o1 = {acc[i][4]+bias[4], acc[i][5]+bias[5], acc[i][6]+bias[6], acc[i][7]+bias[7]};
    *(v4f*)(outp + (size_t)(gm + i) * G4 + gnl) = o0;
    *(v4f*)(outp + (size_t)(gm + i) * G4 + gnh) = o1;
  }
}

// =========================================================
// Persistent BiLSTM recurrence, single-wave blocks.
// 512 blocks x 64 threads: block = dir*256 + bu; owns units {2bu, 2bu+1}
// = 8 gate rows (r = g*2+uu). Lane L holds k-slice [8L, 8L+8) of all 8
// rows in VGPRs. No LDS, no barriers: DPP tree + __shfl exchange only.
// Sync between blocks: data-driven sentinel polling (hs pre-set 0xFF).
// Reduction/summation order is bit-identical to the round-2 kernel.
// =========================================================
__device__ __forceinline__ float row16_sum(float x) {
  x += __int_as_float(__builtin_amdgcn_update_dpp(0, __float_as_int(x), 0x111, 0xf, 0xf, true));
  x += __int_as_float(__builtin_amdgcn_update_dpp(0, __float_as_int(x), 0x112, 0xf, 0xf, true));
  x += __int_as_float(__builtin_amdgcn_update_dpp(0, __float_as_int(x), 0x114, 0xf, 0xf, true));
  x += __int_as_float(__builtin_amdgcn_update_dpp(0, __float_as_int(x), 0x118, 0xf, 0xf, true));
  return x; // lane (16q+15) holds sum of its 16-lane group
}

__device__ __forceinline__ float sigmoidf_(float x) { return 1.f / (1.f + expf(-x)); }

__global__ __launch_bounds__(64) void lstm_kernel(
    const float* __restrict__ h0, const float* __restrict__ c0,
    const float* __restrict__ whhf, const float* __restrict__ whhb,
    const float* __restrict__ xp, float* __restrict__ hs)
{
  const int b = blockIdx.x;
  const int dir = b >> 8, bu = b & 255;
  const int L = threadIdx.x;
  const float* whh = dir ? whhb : whhf;
  const float* xpd = xp + (size_t)dir * T_LEN * G4;
  float* hsd = hs + (size_t)dir * T_LEN * HD;

  // weight preload: rows r=g*2+uu, grow = g*HD + 2*bu + uu
  float wreg[8][8];
  #pragma unroll
  for (int r = 0; r < 8; ++r) {
    const int grow = (r >> 1) * HD + 2 * bu + (r & 1);
    const float* p = whh + (size_t)grow * HD + 8 * L;
    v4f q0 = *(const v4f*)p;
    v4f q1 = *(const v4f*)(p + 4);
    #pragma unroll
    for (int kk = 0; kk < 4; ++kk) { wreg[r][kk] = q0[kk]; wreg[r][4 + kk] = q1[kk]; }
  }
  float cst = (L < 2) ? c0[dir * HD + 2 * bu + L] : 0.f;
  const int growL = (L < 8) ? ((L >> 1) * HD + 2 * bu + (L & 1)) : 0;
  float xpc = 0.f;
  {
    const int t0 = dir ? (T_LEN - 1) : 0;
    if (L < 8) xpc = xpd[(size_t)t0 * G4 + growL];
  }

  for (int s = 0; s < T_LEN; ++s) {
    const int t = dir ? (T_LEN - 1 - s) : s;

    // --- obtain h_prev (data-driven; sentinel 0xFFFFFFFF) ---
    float hr[8];
    if (s == 0) {
      const float* hp = h0 + dir * HD + 8 * L;
      v4f a = *(const v4f*)hp;
      v4f bq = *(const v4f*)(hp + 4);
      #pragma unroll
      for (int kk = 0; kk < 4; ++kk) { hr[kk] = a[kk]; hr[4 + kk] = bq[kk]; }
    } else {
      const int tp = dir ? (t + 1) : (t - 1);
      const float* hp = hsd + (size_t)tp * HD + 8 * L;
      v4i ia, ib;
      do {
        asm volatile("global_load_dwordx4 %0, %2, off sc0 sc1\n"
                     "global_load_dwordx4 %1, %2, off offset:16 sc0 sc1\n"
                     "s_waitcnt vmcnt(0)"
                     : "=&v"(ia), "=&v"(ib) : "v"(hp) : "memory");
      } while (((ia[0] == -1) | (ia[1] == -1) | (ia[2] == -1) | (ia[3] == -1) |
                (ib[0] == -1) | (ib[1] == -1) | (ib[2] == -1) | (ib[3] == -1)) != 0);
      #pragma unroll
      for (int kk = 0; kk < 4; ++kk) {
        hr[kk]     = __int_as_float(ia[kk]);
        hr[4 + kk] = __int_as_float(ib[kk]);
      }
    }

    const float xpv = xpc;                 // xp for this t (prefetched)
    if (L < 8 && s + 1 < T_LEN) {          // prefetch next t
      const int tn = dir ? (t - 1) : (t + 1);
      xpc = xpd[(size_t)tn * G4 + growL];
    }

    // per-lane partial dot for all 8 rows (same k order as before)
    float acc[8];
    #pragma unroll
    for (int r = 0; r < 8; ++r) {
      float a = 0.f;
      #pragma unroll
      for (int kk = 0; kk < 8; ++kk) a = fmaf(wreg[r][kk], hr[kk], a);
      acc[r] = row16_sum(a);
    }
    // ordered cross-group sum ((g0+g1)+g2)+g3 — bit-identical to before
    float tot[8];
    #pragma unroll
    for (int r = 0; r < 8; ++r) {
      const float s0 = __shfl(acc[r], 15);
      const float s1 = __shfl(acc[r], 31);
      const float s2 = __shfl(acc[r], 47);
      const float s3 = __shfl(acc[r], 63);
      tot[r] = ((s0 + s1) + s2) + s3;
    }
    // lane r (<8) selects tot[r]
    const float m01 = (L & 1) ? tot[1] : tot[0];
    const float m23 = (L & 1) ? tot[3] : tot[2];
    const float m45 = (L & 1) ? tot[5] : tot[4];
    const float m67 = (L & 1) ? tot[7] : tot[6];
    const float m03 = (L & 2) ? m23 : m01;
    const float m47 = (L & 2) ? m67 : m45;
    const float mine = (L & 4) ? m47 : m03;

    float gv = 0.f;
    if (L < 8) {
      const float sum = mine + xpv;
      gv = ((L >> 1) == 2) ? tanhf(sum) : sigmoidf_(sum);
    }
    // gather gates to lanes 0,1 (uu = L&1): i@uu, f@2+uu, g@4+uu, o@6+uu
    const float ig = __shfl(gv, (L & 1));
    const float fg = __shfl(gv, (L & 1) + 2);
    const float gg = __shfl(gv, (L & 1) + 4);
    const float og = __shfl(gv, (L & 1) + 6);
    if (L < 2) {
      cst = fg * cst + ig * gg;
      const float hval = og * tanhf(cst);
      float* hp = hsd + (size_t)t * HD + 2 * bu + L;
      asm volatile("global_store_dword %0, %1, off sc0 sc1" :: "v"(hp), "v"(hval) : "memory");
    }
  }
}

// =========================================================
// feats[t][k] = [hs_f[t], hs_b[t]] . w_out[k] + b_out[k]
// =========================================================
__global__ __launch_bounds__(256) void feats_kernel(
    const float* __restrict__ hs, const float* __restrict__ wout,
    const float* __restrict__ bout, float* __restrict__ feats)
{
  __shared__ __align__(16) float xs[32][132];
  __shared__ __align__(16) float wl[34][132];
  const int tid = threadIdx.x;
  const int t0 = blockIdx.x * 32;
  const int m = tid & 31, ng = tid >> 5;
  float acc[5] = {0.f, 0.f, 0.f, 0.f, 0.f};
  for (int cc = 0; cc < 8; ++cc) {
    const int d = cc >> 2;
    const int c0 = (cc & 3) * 128;
    const float* hsrc = hs + (size_t)d * T_LEN * HD;
    const int wcol = d * HD + c0;
    __syncthreads();
    {
      const int row = tid >> 3, seg = tid & 7;
      const float* src = hsrc + (size_t)(t0 + row) * HD + c0 + seg * 16;
      #pragma unroll
      for (int i = 0; i < 4; ++i) {
        v4f v = *(const v4f*)(src + i * 4);
        *(v4f*)&xs[row][seg * 16 + i * 4] = v;
      }
    }
    for (int i = tid; i < 34 * 32; i += 256) {
      const int r = i >> 5, q = i & 31;
      v4f v = *(const v4f*)(wout + (size_t)r * E_DIM + wcol + q * 4);
      *(v4f*)&wl[r][q * 4] = v;
    }
    __syncthreads();
    for (int kq = 0; kq < 32; ++kq) {
      v4f xv = *(const v4f*)&xs[m][kq * 4];
      #pragma unroll
      for (int sl = 0; sl < 5; ++sl) {
        const int n = ng + sl * 8;
        if (n < K_TAGS) {
          v4f wv = *(const v4f*)&wl[n][kq * 4];
          acc[sl] = fmaf(xv[0], wv[0], acc[sl]);
          acc[sl] = fmaf(xv[1], wv[1], acc[sl]);
          acc[sl] = fmaf(xv[2], wv[2], acc[sl]);
          acc[sl] = fmaf(xv[3], wv[3], acc[sl]);
        }
      }
    }
  }
  #pragma unroll
  for (int sl = 0; sl < 5; ++sl) {
    const int n = ng + sl * 8;
    if (n < K_TAGS) feats[(size_t)(t0 + m) * K_TAGS + n] = acc[sl] + bout[n];
  }
}

// =========================================================
// Sequential Viterbi — single wave, no barriers, ordered tree-max
// (bit-identical result & first-max tie-break vs serial scan).
// =========================================================
__global__ __launch_bounds__(64) void viterbi_kernel(
    const float* __restrict__ feats, const float* __restrict__ trans,
    float* __restrict__ d_out, int* __restrict__ bestlast, unsigned char* __restrict__ bp)
{
  const int L = threadIdx.x;
  const int n = (L < K_TAGS) ? L : 0;
  const bool act = (L < K_TAGS);
  float tr[K_TAGS];
  #pragma unroll
  for (int p = 0; p < K_TAGS; ++p) tr[p] = trans[n * K_TAGS + p];
  const float tstop = trans[33 * K_TAGS + n];
  __shared__ float fvs[K_TAGS];
  if (act) fvs[n] = (n == 32) ? 0.f : -10000.f;
  asm volatile("s_waitcnt lgkmcnt(0)" ::: "memory");
  __builtin_amdgcn_sched_barrier(0);

  float feat_next = feats[n];
  float fvreg = 0.f;
  for (int t = 0; t < T_LEN; ++t) {
    const float feat = feat_next;
    if (t + 1 < T_LEN) feat_next = feats[(size_t)(t + 1) * K_TAGS + n];
    float val[K_TAGS];
    int   idx[K_TAGS];
    #pragma unroll
    for (int p = 0; p < K_TAGS; ++p) { val[p] = fvs[p] + tr[p]; idx[p] = p; }
    // ordered tree; right wins only if strictly greater => first-max
    #pragma unroll
    for (int st = 1; st < K_TAGS; st <<= 1) {
      #pragma unroll
      for (int i = 0; i + st < K_TAGS; i += 2 * st) {
        if (val[i + st] > val[i]) { val[i] = val[i + st]; idx[i] = idx[i + st]; }
      }
    }
    fvreg = val[0] + feat;
    if (act) {
      bp[(size_t)t * K_TAGS + n] = (unsigned char)idx[0];
      fvs[n] = fvreg;
    }
    asm volatile("s_waitcnt lgkmcnt(0)" ::: "memory");
    __builtin_amdgcn_sched_barrier(0);
  }
  if (act) fvs[n] = fvreg + tstop;      // terminal scores
  asm volatile("s_waitcnt lgkmcnt(0)" ::: "memory");
  __builtin_amdgcn_sched_barrier(0);
  if (L == 0) {
    float best = -3.4e38f; int bi = 0;
    for (int k = 0; k < K_TAGS; ++k) {
      const float v = fvs[k];
      if (v > best) { best = v; bi = k; }
    }
    d_out[0] = best;
    *bestlast = bi;
  }
}

// =========================================================
// Parallel backtrace: 128 chunks of 64 steps.
// =========================================================
__global__ __launch_bounds__(1024) void backtrace_kernel(
    const unsigned char* __restrict__ bp, const int* __restrict__ bestlast,
    float* __restrict__ d_out)
{
  __shared__ unsigned char exitl[128 * K_TAGS];
  __shared__ unsigned char entl[128];
  const int tid = threadIdx.x;
  for (int W = tid; W < 128 * K_TAGS; W += 1024) {
    const int c = W / K_TAGS;
    int tg = W % K_TAGS;
    for (int t = c * 64 + 63; t >= c * 64; --t) tg = bp[(size_t)t * K_TAGS + tg];
    exitl[W] = (unsigned char)tg;
  }
  __syncthreads();
  if (tid == 0) {
    int tag = *bestlast;
    entl[127] = (unsigned char)tag;
    for (int c = 127; c >= 1; --c) {
      tag = exitl[c * K_TAGS + tag];
      entl[c - 1] = (unsigned char)tag;
    }
  }
  __syncthreads();
  if (tid < 128) {
    const int c = tid;
    int tg = entl[c];
    for (int t = c * 64 + 63; t >= c * 64; --t) {
      d_out[1 + t] = (float)tg;
      tg = bp[(size_t)t * K_TAGS + tg];
    }
  }
}

// =========================================================
extern "C" void kernel_launch(void* const* d_in, const int* in_sizes, int n_in,
                              void* d_out, int out_size, void* d_ws, size_t ws_size,
                              hipStream_t stream)
{
  const float* sent = (const float*)d_in[0];
  const float* h0   = (const float*)d_in[1];
  const float* c0   = (const float*)d_in[2];
  const float* wihf = (const float*)d_in[3];
  const float* whhf = (const float*)d_in[4];
  const float* bihf = (const float*)d_in[5];
  const float* bhhf = (const float*)d_in[6];
  const float* wihb = (const float*)d_in[7];
  const float* whhb = (const float*)d_in[8];
  const float* bihb = (const float*)d_in[9];
  const float* bhhb = (const float*)d_in[10];
  const float* wout = (const float*)d_in[11];
  const float* bout = (const float*)d_in[12];
  const float* trans = (const float*)d_in[13];

  float* out = (float*)d_out;
  char* ws = (char*)d_ws;
  float* xp    = (float*)(ws + XP_OFF);
  float* hs    = (float*)(ws + HS_OFF);
  float* feats = (float*)(ws + FEATS_OFF);
  unsigned char* bp = (unsigned char*)(ws + BP_OFF);
  int* bestlast = (int*)(ws + BEST_OFF);

  // reset hs to the 0xFFFFFFFF sentinel every call (data-driven sync;
  // also makes graph replays deterministic — harness doesn't re-poison)
  hipMemsetAsync(hs, 0xFF, (size_t)2 * T_LEN * HD * sizeof(float), stream);

  // sentence passthrough output
  hipMemcpyAsync(out + 1 + T_LEN, sent, (size_t)T_LEN * E_DIM * sizeof(float),
                 hipMemcpyDeviceToDevice, stream);

  dim3 g1(T_LEN / BM, G4 / BN, 2);
  xp_gemm<<<g1, 256, 0, stream>>>(sent, wihf, wihb, bihf, bhhf, bihb, bhhb, xp);

  lstm_kernel<<<512, 64, 0, stream>>>(h0, c0, whhf, whhb, xp, hs);

  feats_kernel<<<T_LEN / 32, 256, 0, stream>>>(hs, wout, bout, feats);

  viterbi_kernel<<<1, 64, 0, stream>>>(feats, trans, out, bestlast, bp);

  backtrace_kernel<<<1, 1024, 0, stream>>>(bp, bestlast, out);
}

// Round 4
// 19797.139 us; speedup vs baseline: 1.2809x; 1.2809x over previous
//
#include <hip/hip_runtime.h>
#include <hip/hip_bf16.h>

typedef float v4f __attribute__((ext_vector_type(4)));
typedef int   v4i __attribute__((ext_vector_type(4)));

#define T_LEN 8192
#define E_DIM 1024
#define HD    512
#define G4    2048
#define K_TAGS 34

// ---------------- ws layout (bytes) ----------------
#define XP_OFF      0ull                  // 2 * 8192 * 2048 f32 = 128MB
#define HS_OFF      134217728ull          // 2 * 8192 * 512 f32  = 32MB
#define FEATS_OFF   167772160ull          // 8192*34 f32
#define BP_OFF      168886272ull          // 8192*34 u8
#define BEST_OFF    169165824ull          // int

// =========================================================
// xp GEMM: xp[dir][t][r] = sentence[t] . w_ih[dir][r] + b_ih[r]+b_hh[r]
// =========================================================
#define BM 128
#define BN 128
#define BKK 16

__global__ __launch_bounds__(256) void xp_gemm(
    const float* __restrict__ A, const float* __restrict__ Wf, const float* __restrict__ Wb,
    const float* __restrict__ bihf, const float* __restrict__ bhhf,
    const float* __restrict__ bihb, const float* __restrict__ bhhb,
    float* __restrict__ xp)
{
  __shared__ __align__(16) float a_lds[BKK][BM + 4];
  __shared__ __align__(16) float b_lds[BKK][BN + 4];
  const int dir = blockIdx.z;
  const float* W   = dir ? Wb : Wf;
  const float* bih = dir ? bihb : bihf;
  const float* bhh = dir ? bhhb : bhhf;
  const int tid = threadIdx.x;
  const int srow = tid >> 1, sh = (tid & 1) * 8;
  const int tx = tid & 15, ty = tid >> 4;
  const size_t arow = (size_t)(blockIdx.x * BM + srow) * E_DIM;
  const size_t brow = (size_t)(blockIdx.y * BN + srow) * E_DIM;
  float acc[8][8];
  #pragma unroll
  for (int i = 0; i < 8; ++i)
    #pragma unroll
    for (int j = 0; j < 8; ++j) acc[i][j] = 0.f;

  for (int k0 = 0; k0 < E_DIM; k0 += BKK) {
    v4f a0 = *(const v4f*)(A + arow + k0 + sh);
    v4f a1 = *(const v4f*)(A + arow + k0 + sh + 4);
    v4f b0 = *(const v4f*)(W + brow + k0 + sh);
    v4f b1 = *(const v4f*)(W + brow + k0 + sh + 4);
    __syncthreads();
    #pragma unroll
    for (int j = 0; j < 4; ++j) {
      a_lds[sh + j][srow]     = a0[j];
      a_lds[sh + 4 + j][srow] = a1[j];
      b_lds[sh + j][srow]     = b0[j];
      b_lds[sh + 4 + j][srow] = b1[j];
    }
    __syncthreads();
    #pragma unroll
    for (int kk = 0; kk < BKK; ++kk) {
      v4f av0 = *(const v4f*)&a_lds[kk][ty * 8];
      v4f av1 = *(const v4f*)&a_lds[kk][ty * 8 + 4];
      v4f bv0 = *(const v4f*)&b_lds[kk][tx * 4];
      v4f bv1 = *(const v4f*)&b_lds[kk][64 + tx * 4];
      float av[8] = {av0[0],av0[1],av0[2],av0[3],av1[0],av1[1],av1[2],av1[3]};
      float bv[8] = {bv0[0],bv0[1],bv0[2],bv0[3],bv1[0],bv1[1],bv1[2],bv1[3]};
      #pragma unroll
      for (int i = 0; i < 8; ++i)
        #pragma unroll
        for (int j = 0; j < 8; ++j) acc[i][j] = fmaf(av[i], bv[j], acc[i][j]);
    }
  }
  const int gm  = blockIdx.x * BM + ty * 8;
  const int gnl = blockIdx.y * BN + tx * 4;
  const int gnh = gnl + 64;
  float bias[8];
  #pragma unroll
  for (int j = 0; j < 4; ++j) bias[j]     = bih[gnl + j] + bhh[gnl + j];
  #pragma unroll
  for (int j = 0; j < 4; ++j) bias[4 + j] = bih[gnh + j] + bhh[gnh + j];
  float* outp = xp + ((size_t)dir * T_LEN) * G4;
  #pragma unroll
  for (int i = 0; i < 8; ++i) {
    v4f o0 = {acc[i][0]+bias[0], acc[i][1]+bias[1], acc[i][2]+bias[2], acc[i][3]+bias[3]};
    v4f o1 = {acc[i][4]+bias[4], acc[i][5]+bias[5], acc[i][6]+bias[6], acc[i][7]+bias[7]};
    *(v4f*)(outp + (size_t)(gm + i) * G4 + gnl) = o0;
    *(v4f*)(outp + (size_t)(gm + i) * G4 + gnh) = o1;
  }
}

// =========================================================
// Persistent BiLSTM recurrence. 64 blocks (32/dir) x 1024 threads.
// Round-2 structure with two fixes:
//  - ONLY wave0 polls h_prev (64 lanes x 8 floats = one full row),
//    broadcast via LDS hl[] — 16x less sc1 poll traffic than round 2.
//  - Producer stores stay 16-dword coalesced pieces (32 pieces/row).
// Sync between blocks: data-driven sentinel polling (hs pre-set 0xFF).
// =========================================================
__device__ __forceinline__ float row16_sum(float x) {
  x += __int_as_float(__builtin_amdgcn_update_dpp(0, __float_as_int(x), 0x111, 0xf, 0xf, true));
  x += __int_as_float(__builtin_amdgcn_update_dpp(0, __float_as_int(x), 0x112, 0xf, 0xf, true));
  x += __int_as_float(__builtin_amdgcn_update_dpp(0, __float_as_int(x), 0x114, 0xf, 0xf, true));
  x += __int_as_float(__builtin_amdgcn_update_dpp(0, __float_as_int(x), 0x118, 0xf, 0xf, true));
  return x; // lane (16q+15) holds sum of its 16-lane group
}

__device__ __forceinline__ float sigmoidf_(float x) { return 1.f / (1.f + expf(-x)); }

__global__ __launch_bounds__(1024) void lstm_kernel(
    const float* __restrict__ h0, const float* __restrict__ c0,
    const float* __restrict__ whhf, const float* __restrict__ whhb,
    const float* __restrict__ xp, float* __restrict__ hs)
{
  const int b = blockIdx.x;
  const int dir = b >> 5, bb = b & 31;
  const int tid = threadIdx.x;
  const int w = tid >> 6, L = tid & 63;
  const float* whh = dir ? whhb : whhf;
  const float* xpd = xp + (size_t)dir * T_LEN * G4;
  float* hsd = hs + (size_t)dir * T_LEN * HD;
  __shared__ __align__(16) float red2[16][4][4];
  __shared__ __align__(16) float hl[HD];
  __shared__ float xpl[2][64];
  __shared__ float gl[4][16];

  // weight preload into VGPRs: wave w owns gate rows 4w..4w+3
  float wreg[4][8];
  #pragma unroll
  for (int j = 0; j < 4; ++j) {
    int r = 4 * w + j;
    int grow = (r >> 4) * HD + bb * 16 + (r & 15);
    const float* p = whh + (size_t)grow * HD + 8 * L;
    v4f q0 = *(const v4f*)p;
    v4f q1 = *(const v4f*)(p + 4);
    #pragma unroll
    for (int kk = 0; kk < 4; ++kk) { wreg[j][kk] = q0[kk]; wreg[j][4 + kk] = q1[kk]; }
  }
  float cst = (tid < 16) ? c0[dir * HD + bb * 16 + tid] : 0.f;
  if (tid >= 64 && tid < 128) {  // prefetch xp row for s=0
    int r = tid - 64;
    int col = (r >> 4) * HD + bb * 16 + (r & 15);
    int t0 = dir ? (T_LEN - 1) : 0;
    xpl[0][r] = xpd[(size_t)t0 * G4 + col];
  }
  __syncthreads();

  for (int s = 0; s < T_LEN; ++s) {
    const int t = dir ? (T_LEN - 1 - s) : s;

    // --- wave0: obtain h_prev (sentinel polling) and publish to LDS ---
    if (w == 0) {
      if (s == 0) {
        const float* hp = h0 + dir * HD + 8 * L;
        v4f a = *(const v4f*)hp;
        v4f bq = *(const v4f*)(hp + 4);
        *(v4f*)&hl[8 * L]     = a;
        *(v4f*)&hl[8 * L + 4] = bq;
      } else {
        const int tp = dir ? (t + 1) : (t - 1);
        const float* hp = hsd + (size_t)tp * HD + 8 * L;
        v4i ia, ib;
        do {
          asm volatile("global_load_dwordx4 %0, %2, off sc0 sc1\n"
                       "global_load_dwordx4 %1, %2, off offset:16 sc0 sc1\n"
                       "s_waitcnt vmcnt(0)"
                       : "=&v"(ia), "=&v"(ib) : "v"(hp) : "memory");
        } while (((ia[0] == -1) | (ia[1] == -1) | (ia[2] == -1) | (ia[3] == -1) |
                  (ib[0] == -1) | (ib[1] == -1) | (ib[2] == -1) | (ib[3] == -1)) != 0);
        v4f fa, fb;
        #pragma unroll
        for (int kk = 0; kk < 4; ++kk) { fa[kk] = __int_as_float(ia[kk]); fb[kk] = __int_as_float(ib[kk]); }
        *(v4f*)&hl[8 * L]     = fa;
        *(v4f*)&hl[8 * L + 4] = fb;
      }
    }
    __syncthreads();  // B1: hl visible to all waves

    // --- all 16 waves: partial dots for their 4 gate rows ---
    v4f h0v = *(const v4f*)&hl[8 * L];
    v4f h1v = *(const v4f*)&hl[8 * L + 4];
    float hr[8] = {h0v[0], h0v[1], h0v[2], h0v[3], h1v[0], h1v[1], h1v[2], h1v[3]};
    float a4[4];
    #pragma unroll
    for (int j = 0; j < 4; ++j) {
      float a = 0.f;
      #pragma unroll
      for (int kk = 0; kk < 8; ++kk) a = fmaf(wreg[j][kk], hr[kk], a);
      a4[j] = row16_sum(a);
    }
    if ((L & 15) == 15) {
      int q = L >> 4;
      v4f rv = {a4[0], a4[1], a4[2], a4[3]};
      *(v4f*)&red2[w][q][0] = rv;
    }
    __syncthreads();  // B2: red2 complete

    if (tid < 64) {
      // one gate row per lane of wave 0 (parallel nonlinearities)
      const int u = tid & 15, g = tid >> 4;
      const int r = g * 16 + u;
      const int ww = r >> 2, j = r & 3;
      const float sum = red2[ww][0][j] + red2[ww][1][j] + red2[ww][2][j] + red2[ww][3][j]
                      + xpl[s & 1][r];
      const float gv = (g == 2) ? tanhf(sum) : sigmoidf_(sum);
      gl[g][u] = gv;
      asm volatile("s_waitcnt lgkmcnt(0)" ::: "memory");  // same-wave LDS ordering
      if (tid < 16) {
        const float ig = gl[0][u];
        const float fg = gl[1][u];
        const float gg = gl[2][u];
        const float og = gl[3][u];
        cst = fg * cst + ig * gg;
        const float hval = og * tanhf(cst);
        float* hp = hsd + (size_t)t * HD + bb * 16 + u;
        asm volatile("global_store_dword %0, %1, off sc0 sc1" :: "v"(hp), "v"(hval) : "memory");
      }
    } else if (tid >= 64 && tid < 128 && s + 1 < T_LEN) {
      const int r = tid - 64;
      const int col = (r >> 4) * HD + bb * 16 + (r & 15);
      const int tn = dir ? (t - 1) : (t + 1);
      xpl[(s + 1) & 1][r] = xpd[(size_t)tn * G4 + col];
    }
  }
}

// =========================================================
// feats[t][k] = [hs_f[t], hs_b[t]] . w_out[k] + b_out[k]
// =========================================================
__global__ __launch_bounds__(256) void feats_kernel(
    const float* __restrict__ hs, const float* __restrict__ wout,
    const float* __restrict__ bout, float* __restrict__ feats)
{
  __shared__ __align__(16) float xs[32][132];
  __shared__ __align__(16) float wl[34][132];
  const int tid = threadIdx.x;
  const int t0 = blockIdx.x * 32;
  const int m = tid & 31, ng = tid >> 5;
  float acc[5] = {0.f, 0.f, 0.f, 0.f, 0.f};
  for (int cc = 0; cc < 8; ++cc) {
    const int d = cc >> 2;
    const int c0 = (cc & 3) * 128;
    const float* hsrc = hs + (size_t)d * T_LEN * HD;
    const int wcol = d * HD + c0;
    __syncthreads();
    {
      const int row = tid >> 3, seg = tid & 7;
      const float* src = hsrc + (size_t)(t0 + row) * HD + c0 + seg * 16;
      #pragma unroll
      for (int i = 0; i < 4; ++i) {
        v4f v = *(const v4f*)(src + i * 4);
        *(v4f*)&xs[row][seg * 16 + i * 4] = v;
      }
    }
    for (int i = tid; i < 34 * 32; i += 256) {
      const int r = i >> 5, q = i & 31;
      v4f v = *(const v4f*)(wout + (size_t)r * E_DIM + wcol + q * 4);
      *(v4f*)&wl[r][q * 4] = v;
    }
    __syncthreads();
    for (int kq = 0; kq < 32; ++kq) {
      v4f xv = *(const v4f*)&xs[m][kq * 4];
      #pragma unroll
      for (int sl = 0; sl < 5; ++sl) {
        const int n = ng + sl * 8;
        if (n < K_TAGS) {
          v4f wv = *(const v4f*)&wl[n][kq * 4];
          acc[sl] = fmaf(xv[0], wv[0], acc[sl]);
          acc[sl] = fmaf(xv[1], wv[1], acc[sl]);
          acc[sl] = fmaf(xv[2], wv[2], acc[sl]);
          acc[sl] = fmaf(xv[3], wv[3], acc[sl]);
        }
      }
    }
  }
  #pragma unroll
  for (int sl = 0; sl < 5; ++sl) {
    const int n = ng + sl * 8;
    if (n < K_TAGS) feats[(size_t)(t0 + m) * K_TAGS + n] = acc[sl] + bout[n];
  }
}

// =========================================================
// Sequential Viterbi — single wave, no barriers, ordered tree-max
// (first-max tie-break preserved vs np.argmax).
// =========================================================
__global__ __launch_bounds__(64) void viterbi_kernel(
    const float* __restrict__ feats, const float* __restrict__ trans,
    float* __restrict__ d_out, int* __restrict__ bestlast, unsigned char* __restrict__ bp)
{
  const int L = threadIdx.x;
  const int n = (L < K_TAGS) ? L : 0;
  const bool act = (L < K_TAGS);
  float tr[K_TAGS];
  #pragma unroll
  for (int p = 0; p < K_TAGS; ++p) tr[p] = trans[n * K_TAGS + p];
  const float tstop = trans[33 * K_TAGS + n];
  __shared__ float fvs[K_TAGS];
  if (act) fvs[n] = (n == 32) ? 0.f : -10000.f;
  asm volatile("s_waitcnt lgkmcnt(0)" ::: "memory");
  __builtin_amdgcn_sched_barrier(0);

  float feat_next = feats[n];
  float fvreg = 0.f;
  for (int t = 0; t < T_LEN; ++t) {
    const float feat = feat_next;
    if (t + 1 < T_LEN) feat_next = feats[(size_t)(t + 1) * K_TAGS + n];
    float val[K_TAGS];
    int   idx[K_TAGS];
    #pragma unroll
    for (int p = 0; p < K_TAGS; ++p) { val[p] = fvs[p] + tr[p]; idx[p] = p; }
    // ordered tree; right wins only if strictly greater => first-max
    #pragma unroll
    for (int st = 1; st < K_TAGS; st <<= 1) {
      #pragma unroll
      for (int i = 0; i + st < K_TAGS; i += 2 * st) {
        if (val[i + st] > val[i]) { val[i] = val[i + st]; idx[i] = idx[i + st]; }
      }
    }
    fvreg = val[0] + feat;
    if (act) {
      bp[(size_t)t * K_TAGS + n] = (unsigned char)idx[0];
      fvs[n] = fvreg;
    }
    asm volatile("s_waitcnt lgkmcnt(0)" ::: "memory");
    __builtin_amdgcn_sched_barrier(0);
  }
  if (act) fvs[n] = fvreg + tstop;      // terminal scores
  asm volatile("s_waitcnt lgkmcnt(0)" ::: "memory");
  __builtin_amdgcn_sched_barrier(0);
  if (L == 0) {
    float best = -3.4e38f; int bi = 0;
    for (int k = 0; k < K_TAGS; ++k) {
      const float v = fvs[k];
      if (v > best) { best = v; bi = k; }
    }
    d_out[0] = best;
    *bestlast = bi;
  }
}

// =========================================================
// Parallel backtrace: 128 chunks of 64 steps.
// =========================================================
__global__ __launch_bounds__(1024) void backtrace_kernel(
    const unsigned char* __restrict__ bp, const int* __restrict__ bestlast,
    float* __restrict__ d_out)
{
  __shared__ unsigned char exitl[128 * K_TAGS];
  __shared__ unsigned char entl[128];
  const int tid = threadIdx.x;
  for (int W = tid; W < 128 * K_TAGS; W += 1024) {
    const int c = W / K_TAGS;
    int tg = W % K_TAGS;
    for (int t = c * 64 + 63; t >= c * 64; --t) tg = bp[(size_t)t * K_TAGS + tg];
    exitl[W] = (unsigned char)tg;
  }
  __syncthreads();
  if (tid == 0) {
    int tag = *bestlast;
    entl[127] = (unsigned char)tag;
    for (int c = 127; c >= 1; --c) {
      tag = exitl[c * K_TAGS + tag];
      entl[c - 1] = (unsigned char)tag;
    }
  }
  __syncthreads();
  if (tid < 128) {
    const int c = tid;
    int tg = entl[c];
    for (int t = c * 64 + 63; t >= c * 64; --t) {
      d_out[1 + t] = (float)tg;
      tg = bp[(size_t)t * K_TAGS + tg];
    }
  }
}

// =========================================================
extern "C" void kernel_launch(void* const* d_in, const int* in_sizes, int n_in,
                              void* d_out, int out_size, void* d_ws, size_t ws_size,
                              hipStream_t stream)
{
  const float* sent = (const float*)d_in[0];
  const float* h0   = (const float*)d_in[1];
  const float* c0   = (const float*)d_in[2];
  const float* wihf = (const float*)d_in[3];
  const float* whhf = (const float*)d_in[4];
  const float* bihf = (const float*)d_in[5];
  const float* bhhf = (const float*)d_in[6];
  const float* wihb = (const float*)d_in[7];
  const float* whhb = (const float*)d_in[8];
  const float* bihb = (const float*)d_in[9];
  const float* bhhb = (const float*)d_in[10];
  const float* wout = (const float*)d_in[11];
  const float* bout = (const float*)d_in[12];
  const float* trans = (const float*)d_in[13];

  float* out = (float*)d_out;
  char* ws = (char*)d_ws;
  float* xp    = (float*)(ws + XP_OFF);
  float* hs    = (float*)(ws + HS_OFF);
  float* feats = (float*)(ws + FEATS_OFF);
  unsigned char* bp = (unsigned char*)(ws + BP_OFF);
  int* bestlast = (int*)(ws + BEST_OFF);

  // reset hs to the 0xFFFFFFFF sentinel every call (data-driven sync;
  // also makes graph replays deterministic — harness doesn't re-poison)
  hipMemsetAsync(hs, 0xFF, (size_t)2 * T_LEN * HD * sizeof(float), stream);

  // sentence passthrough output
  hipMemcpyAsync(out + 1 + T_LEN, sent, (size_t)T_LEN * E_DIM * sizeof(float),
                 hipMemcpyDeviceToDevice, stream);

  dim3 g1(T_LEN / BM, G4 / BN, 2);
  xp_gemm<<<g1, 256, 0, stream>>>(sent, wihf, wihb, bihf, bhhf, bihb, bhhb, xp);

  lstm_kernel<<<64, 1024, 0, stream>>>(h0, c0, whhf, whhb, xp, hs);

  feats_kernel<<<T_LEN / 32, 256, 0, stream>>>(hs, wout, bout, feats);

  viterbi_kernel<<<1, 64, 0, stream>>>(feats, trans, out, bestlast, bp);

  backtrace_kernel<<<1, 1024, 0, stream>>>(bp, bestlast, out);
}